// Round 18
// baseline (38.401 us; speedup 1.0000x reference)
//
#include <hip/hip_runtime.h>

#define B_TOTAL 32768
#define NROWB   128            // rows per block
#define TILE    16             // rows per tile
#define NT      8              // tiles per block

typedef __attribute__((ext_vector_type(8)))  short    bf16x8;
typedef __attribute__((ext_vector_type(4)))  float    f32x4;
typedef __attribute__((ext_vector_type(2)))  unsigned u32x2;
typedef __attribute__((ext_vector_type(4)))  unsigned u32x4;

// round-to-nearest-even fp32 -> bf16 (weights, one-time)
__device__ __forceinline__ unsigned rne1(float f) {
    unsigned u = __builtin_bit_cast(unsigned, f);
    return (u + 0x7FFFu + ((u >> 16) & 1u)) >> 16;
}
// HW packed fp32x2 -> bf16x2 (gfx950; no builtin)
__device__ __forceinline__ unsigned cvtpk(float lo, float hi) {
    unsigned r;
    asm("v_cvt_pk_bf16_f32 %0, %1, %2" : "=v"(r) : "v"(lo), "v"(hi));
    return r;
}
__device__ __forceinline__ float fsig(float v) {
    return __fdividef(1.0f, 1.0f + __expf(-v));
}
__device__ __forceinline__ float ftanh(float v) {
    return 1.0f - __fdividef(2.0f, 1.0f + __expf(2.0f * v));
}

// Weights -> COMPOSITE gate-interleaved fragments for mfma 16x16x32 (R8's
// verified layout).  Frag F = (s*2 + tau)*8 + ks, s = 8-hcol slice 0..15.
// B-col n16 = hl*4 + g  ->  D's j-index gives a lane all 4 GATES of one hcol.
// Lane l: n16 = l&15 -> g = n16&3, hl = n16>>2;
//   element = W_g[hcol = s*8 + tau*4 + hl][k = ks*32 + (l>>4)*8 + e]
__global__ void wconv_kernel(const float* __restrict__ w1, const float* __restrict__ w2,
                             const float* __restrict__ wf, const float* __restrict__ w3,
                             u32x4* __restrict__ out) {
    int T = blockIdx.x * 256 + threadIdx.x;   // 16384 threads
    int F = T >> 6, l = T & 63;
    int s = F >> 4, tau = (F >> 3) & 1, ks = F & 7;
    int n16 = l & 15;
    int g = n16 & 3, hl = n16 >> 2;
    const float* W = (g == 0) ? w1 : (g == 1) ? w2 : (g == 2) ? wf : w3;
    const float* src = W + (s * 8 + tau * 4 + hl) * 256 + ks * 32 + (l >> 4) * 8;
    f32x4 lo = *(const f32x4*)src;
    f32x4 hi = *(const f32x4*)(src + 4);
    u32x4 r;
    r[0] = rne1(lo[0]) | (rne1(lo[1]) << 16);
    r[1] = rne1(lo[2]) | (rne1(lo[3]) << 16);
    r[2] = rne1(hi[0]) | (rne1(hi[1]) << 16);
    r[3] = rne1(hi[2]) | (rne1(hi[3]) << 16);
    out[T] = r;
}

// R18 = R16/R17 (bf16 convert-once LDS staging, rotated slots) + R8
// (composite gates: 64 weight VGPRs/wave) + 4 waves/SIMD.
// Block: 1024 thr = 16 waves = all 128 cols (x/h staged ONCE); wave w owns
// 8 hcols x 4 gates AND stages row w of each 16-row tile (1 coalesced 16B
// load/lane/tile). launch_bounds(1024,4): VGPR cap 128, est. use ~115.
// Hot loop/wave-tile: 8 ds_read_b128 (2-way) + 16 MFMA, zero cvtpk.
__global__ __launch_bounds__(1024, 4) void lstm_kernel(
    const float* __restrict__ x, const float* __restrict__ h, const float* __restrict__ c,
    const bf16x8* __restrict__ wfrag,
    const float* __restrict__ b1, const float* __restrict__ b2,
    const float* __restrict__ bfv, const float* __restrict__ b3,
    float* __restrict__ out)
{
    __shared__ __align__(16) char smem[2][8192];   // 16 KB bf16 A dbuf

    const int tid  = threadIdx.x;
    const int wave = tid >> 6;                // col-slice s = wave (0..15)
    const int lane = tid & 63;
    const int rb   = lane & 15;               // batch row within tile
    const int c4   = lane >> 4;               // 0..3 = local hcol
    const long row0 = (long)blockIdx.x * NROWB;
    const int col0 = wave * 8 + c4;           // tau=0 output col
    const int col1 = col0 + 4;                // tau=1 output col

    // ---- staging map: wave w stages row w; lane covers 4 fp32 ----
    // ks = lane&7 (so a 16-lane phase spans all bank-quads), chunk = lane>>3.
    // slot s16 = (ksub<<4)|row16, stored rotated: ((s16 + ks)&63)*16 (+half*8).
    const int ksst  = lane & 7;
    const int chunk = lane >> 3;              // 0..7
    const int k0    = ksst * 32 + chunk * 4;  // fp32 index in row
    const int stoff = ksst * 1024
        + (((((chunk >> 1) << 4) | wave) + ksst) & 63) * 16
        + (chunk & 1) * 8;

    f32x4 ar;                                 // 4 fp32 in flight
    auto A_ISSUE = [&](int t) {
        const float* base = (k0 < 128)
            ? (x + (row0 + (long)t * TILE + wave) * 128 + k0)
            : (h + (row0 + (long)t * TILE + wave) * 128 + (k0 - 128));
        ar = *(const f32x4*)base;
    };
    auto A_STORE = [&](int b) {
        u32x2 w;
        w[0] = cvtpk(ar[0], ar[1]);
        w[1] = cvtpk(ar[2], ar[3]);
        *(u32x2*)(smem[b & 1] + stoff) = w;
    };

    // ---- prologue ----
    A_ISSUE(0);

    bf16x8 wfr[2][8];                         // composite weights: 64 VGPRs
#pragma unroll
    for (int tau = 0; tau < 2; ++tau)
#pragma unroll
        for (int ks = 0; ks < 8; ++ks)
            wfr[tau][ks] = wfrag[(size_t)((wave * 2 + tau) * 8 + ks) * 64 + lane];

    const f32x4 bias0 = (f32x4){ b1[col0], b2[col0], bfv[col0], b3[col0] };
    const f32x4 bias1 = (f32x4){ b1[col1], b2[col1], bfv[col1], b3[col1] };

    A_STORE(0);
    A_ISSUE(1);

    float cv0 = c[(row0 + rb) * 128 + col0];
    float cv1 = c[(row0 + rb) * 128 + col1];

    float* out_h = out;
    float* out_c = out + (size_t)B_TOTAL * 128;

#pragma unroll 1
    for (int t = 0; t < NT; ++t) {
        asm volatile("s_waitcnt lgkmcnt(0)" ::: "memory");   // my ds ops done
        __builtin_amdgcn_s_barrier();          // buf[t&1] complete block-wide
        __builtin_amdgcn_sched_barrier(0);

        const char* buf = smem[t & 1];
        const long gr0 = row0 + (long)t * TILE;

        f32x4 acc0 = bias0, acc1 = bias1;      // 4 gates x (col0 | col1)

#pragma unroll
        for (int ks = 0; ks < 8; ++ks) {
            bf16x8 af = *(const bf16x8*)(buf + ks * 1024 + ((lane + ks) & 63) * 16);
            acc0 = __builtin_amdgcn_mfma_f32_16x16x32_bf16(wfr[0][ks], af, acc0, 0, 0, 0);
            acc1 = __builtin_amdgcn_mfma_f32_16x16x32_bf16(wfr[1][ks], af, acc1, 0, 0, 0);
        }

        // stage t+1 (ds_write overlaps epilogue; fenced by next lgkmcnt(0))
        if (t + 1 < NT) {
            A_STORE(t + 1);
            if (t + 2 < NT) A_ISSUE(t + 2);
        }

        // c prefetch for next tile (clamped at tail)
        const int tn = (t + 1 < NT) ? (t + 1) : (NT - 1);
        const float ncv0 = c[(row0 + (long)tn * TILE + rb) * 128 + col0];
        const float ncv1 = c[(row0 + (long)tn * TILE + rb) * 128 + col1];

        // epilogue: lane holds all 4 gates of (row rb, col0) and (row rb, col1)
        const long orow = (gr0 + rb) * 128;
        {
            const float G1 = fsig(acc0[0]);
            const float G2 = fsig(acc0[1]);
            const float GF = ftanh(acc0[2]);
            const float G3 = fsig(acc0[3]);
            const float nc = cv0 * G1 + G2 * GF;
            out_h[orow + col0] = ftanh(nc) * G3;
            out_c[orow + col0] = nc;
        }
        {
            const float G1 = fsig(acc1[0]);
            const float G2 = fsig(acc1[1]);
            const float GF = ftanh(acc1[2]);
            const float G3 = fsig(acc1[3]);
            const float nc = cv1 * G1 + G2 * GF;
            out_h[orow + col1] = ftanh(nc) * G3;
            out_c[orow + col1] = nc;
        }

        cv0 = ncv0;
        cv1 = ncv1;
    }
}

extern "C" void kernel_launch(void* const* d_in, const int* in_sizes, int n_in,
                              void* d_out, int out_size, void* d_ws, size_t ws_size,
                              hipStream_t stream) {
    (void)in_sizes; (void)n_in; (void)out_size; (void)ws_size;
    const float* x  = (const float*)d_in[0];
    const float* h  = (const float*)d_in[1];
    const float* c  = (const float*)d_in[2];
    const float* W1 = (const float*)d_in[3];
    const float* b1 = (const float*)d_in[4];
    const float* W2 = (const float*)d_in[5];
    const float* b2 = (const float*)d_in[6];
    const float* Wf = (const float*)d_in[7];
    const float* bf = (const float*)d_in[8];
    const float* W3 = (const float*)d_in[9];
    const float* b3 = (const float*)d_in[10];

    wconv_kernel<<<64, 256, 0, stream>>>(W1, W2, Wf, W3, (u32x4*)d_ws);
    lstm_kernel<<<B_TOTAL / NROWB, 1024, 0, stream>>>(
        x, h, c, (const bf16x8*)d_ws, b1, b2, bf, b3, (float*)d_out);
}